// Round 5
// baseline (1027.363 us; speedup 1.0000x reference)
//
#include <hip/hip_runtime.h>
#include <stdint.h>

// Problem constants
#define CKP 128          // packed K (mk ; mk^2)
#define OCV 1024         // O*CV
#define NTOT 25920       // T*H*W
#define HW 1620
#define HWP 1664         // padded to 13*128
#define QT 128           // q tile
#define VT 256           // v tile
#define NC 32            // n chunk (halved: 2 blocks/CU)
#define NQT 13
#define NS 4
#define CHUNKS_TOTAL 810 // NTOT/NC
#define CPN 203          // chunks per nsp split

typedef _Float16 f16x8 __attribute__((ext_vector_type(8)));
typedef _Float16 f16x4 __attribute__((ext_vector_type(4)));
typedef float f32x4 __attribute__((ext_vector_type(4)));

__device__ __forceinline__ void gload_lds16(const void* g, void* l) {
  __builtin_amdgcn_global_load_lds(
      (const __attribute__((address_space(1))) uint32_t*)g,
      (__attribute__((address_space(3))) uint32_t*)l, 16, 0, 0);
}

// ---- prep: memory_value fp32 -> fp16
__global__ void k_prep_mv(const float* __restrict__ mv, _Float16* __restrict__ mvh) {
  int i = blockIdx.x * 256 + threadIdx.x;
  const float4* s = (const float4*)mv + (size_t)i * 2;
  float4 a = s[0], b = s[1];
  f16x8 o;
  o[0]=(_Float16)a.x; o[1]=(_Float16)a.y; o[2]=(_Float16)a.z; o[3]=(_Float16)a.w;
  o[4]=(_Float16)b.x; o[5]=(_Float16)b.y; o[6]=(_Float16)b.z; o[7]=(_Float16)b.w;
  *((f16x8*)mvh + i) = o;
}

// ---- prep: memory_key -> MKpack[b][n][k] fp16 (rows mk ; mk^2)
__global__ void k_prep_mk(const float* __restrict__ mk, _Float16* __restrict__ mkp) {
  __shared__ _Float16 LT[64 * CKP];
  int b = blockIdx.y, n0 = blockIdx.x * 64;
  int c4 = threadIdx.x >> 6, nl = threadIdx.x & 63;
  for (int c = c4; c < 64; c += 4) {
    float v = mk[((size_t)(b * 64 + c)) * NTOT + n0 + nl];
    LT[nl * CKP + c]      = (_Float16)v;
    LT[nl * CKP + 64 + c] = (_Float16)(v * v);
  }
  __syncthreads();
  #pragma unroll
  for (int k = 0; k < 4; ++k) {
    int idx = threadIdx.x + 256 * k;
    int n = idx >> 4, c16 = idx & 15;
    *((uint4*)(mkp + ((size_t)b * NTOT + n0 + n) * CKP + c16 * 8)) =
        *((const uint4*)(&LT[n * CKP + c16 * 8]));
  }
}

// ---- prep: Qpack[b][q][k] fp16 (rows 2*qk*qe ; -qe), bsq fp32; pad q>=1620 with 0
__global__ void k_prep_q(const float* __restrict__ qk, const float* __restrict__ qe,
                         _Float16* __restrict__ qp, float* __restrict__ bsq) {
  __shared__ _Float16 LT[QT * CKP];
  int b = blockIdx.y, q0 = blockIdx.x * QT;
  int t = threadIdx.x;
  int q = q0 + t;
  bool valid = q < HW;
  float acc = 0.f;
  for (int c = 0; c < 64; ++c) {
    float a = valid ? qk[((size_t)(b * 64 + c)) * HW + q] : 0.f;
    float e = valid ? qe[((size_t)(b * 64 + c)) * HW + q] : 0.f;
    LT[t * CKP + c]      = (_Float16)(2.f * a * e);
    LT[t * CKP + 64 + c] = (_Float16)(-e);
    acc += e * a * a;
  }
  bsq[(size_t)b * HWP + q] = acc;
  __syncthreads();
  #pragma unroll
  for (int k = 0; k < 16; ++k) {
    int idx = t + 128 * k;
    int qq = idx >> 4, c16 = idx & 15;
    *((uint4*)(qp + ((size_t)b * HWP + q0 + qq) * CKP + c16 * 8)) =
        *((const uint4*)(&LT[qq * CKP + c16 * 8]));
  }
}

// ---- fused main. NC=32 chunks, LDS 68KB -> 2 blocks/CU (16 waves/CU).
// Grid 416 = 8 xcds x 52. xcd = wgid&7 carries (b,nsp): all blocks on an XCD
// share the MK chunk stream; 13 qt-blocks share each MV stream.
__launch_bounds__(512, 4)
__global__ void k_main(const _Float16* __restrict__ mvh, const _Float16* __restrict__ mkp,
                       const _Float16* __restrict__ qp, const float* __restrict__ bsq,
                       const float* __restrict__ ms,
                       float* __restrict__ pO, float* __restrict__ lpart) {
  const int wgid = blockIdx.x;
  const int xcd = wgid & 7, kk = wgid >> 3;    // kk in 0..51
  const int b = xcd >> 2, nsp = xcd & 3;
  const int vt = kk / NQT, qt = kk % NQT;

  const int tid = threadIdx.x;
  const int w = tid >> 6, l = tid & 63;
  const int l15 = l & 15, g = l >> 4;

  __shared__ _Float16 MVs[2][VT * NC];   // 2x16KB, linear dest, source pre-swizzled
  __shared__ _Float16 MKs[2][NC * CKP];  // 2x8KB
  __shared__ _Float16 Ps[2][QT * NC];    // 2x8KB
  __shared__ float lred[QT * 8];

  const int qw = w & 3, nh = w >> 2;     // S-phase wave roles (nh: n-half of 16)
  const int wv = w & 3, wq = w >> 2;     // readout roles

  const int cBeg = nsp * CPN;
  int ce = cBeg + CPN; if (ce > CHUNKS_TOTAL) ce = CHUNKS_TOTAL;
  const int cEnd = ce;

  // async-staging bases (chunk 0) + linear LDS byte offsets
  // MV tile: 256 rows x 32 f16 (64B) = 1024 16B-slots; slot s holds global
  // k-group j = s ^ ((v>>1)&3)  (read side applies the same XOR).
  const char* mvb[2]; int dmv[2];
  #pragma unroll
  for (int k = 0; k < 2; ++k) {
    int idx = k * 512 + tid;
    int v = idx >> 2, s = idx & 3, j = s ^ ((v >> 1) & 3);
    mvb[k] = (const char*)(mvh + ((size_t)b * OCV + vt * VT + v) * NTOT + j * 8);
    dmv[k] = idx * 16;
  }
  // MK tile: 32 rows x 128 f16 (256B) = 512 slots; j = s ^ (n&7).
  const char* mkb; int dmk;
  {
    int idx = tid;
    int n = idx >> 4, s = idx & 15, j = s ^ (n & 7);
    mkb = (const char*)(mkp + ((size_t)b * NTOT + n) * CKP + j * 8);
    dmk = idx * 16;
  }
  const float* msb = ms + (size_t)b * NTOT + nh * 16 + g * 4;

  // Q fragments + bsq in registers (chunk-invariant)
  f16x8 qreg[2][4];
  float bq[2];
  #pragma unroll
  for (int j = 0; j < 2; ++j) {
    int q_loc = qw * 32 + j * 16 + l15;
    const _Float16* qrow = qp + ((size_t)b * HWP + qt * QT + q_loc) * CKP;
    #pragma unroll
    for (int ks = 0; ks < 4; ++ks) qreg[j][ks] = *((const f16x8*)(qrow + (ks * 4 + g) * 8));
    bq[j] = bsq[(size_t)b * HWP + qt * QT + q_loc];
  }

  f32x4 acc[4][4];
  #pragma unroll
  for (int i = 0; i < 4; ++i)
    #pragma unroll
    for (int j = 0; j < 4; ++j) acc[i][j] = (f32x4)0.f;
  float lp0 = 0.f, lp1 = 0.f;

  auto stage_mv = [&](int ch, int buf) {
    size_t o = (size_t)ch * (NC * 2);
    char* d = (char*)MVs[buf];
    #pragma unroll
    for (int k = 0; k < 2; ++k) gload_lds16(mvb[k] + o, d + dmv[k]);
  };
  auto stage_mk = [&](int ch, int buf) {
    size_t o = (size_t)ch * (NC * CKP * 2);
    gload_lds16(mkb + o, (char*)MKs[buf] + dmk);
  };

  // S = MK x Q over K=128 for a 32n x 128q tile; each wave: 16n x 32q.
  auto do_S = [&](int kb, int pb, float4 mA) {
    const _Float16* MKc = MKs[kb];
    f32x4 sacc[2];
    sacc[0] = (f32x4)0.f; sacc[1] = (f32x4)0.f;
    const int n_loc = nh * 16 + l15;
    __builtin_amdgcn_s_setprio(1);
    #pragma unroll
    for (int ks = 0; ks < 4; ++ks) {
      f16x8 af = *((const f16x8*)(&MKc[n_loc * CKP + (((ks * 4 + g) ^ (n_loc & 7)) * 8)]));
      #pragma unroll
      for (int j = 0; j < 2; ++j)
        sacc[j] = __builtin_amdgcn_mfma_f32_16x16x32_f16(af, qreg[j][ks], sacc[j], 0, 0, 0);
    }
    __builtin_amdgcn_s_setprio(0);
    const float K = 0.125f * 1.44269504f;
    const int nbase = nh * 16 + g * 4;
    float m0 = mA.x * K, m1 = mA.y * K, m2 = mA.z * K, m3 = mA.w * K;
    #pragma unroll
    for (int j = 0; j < 2; ++j) {
      int q_loc = qw * 32 + j * 16 + l15;
      float bqv = bq[j];
      float p0 = exp2f((sacc[j][0] - bqv) * m0);
      float p1 = exp2f((sacc[j][1] - bqv) * m1);
      float p2 = exp2f((sacc[j][2] - bqv) * m2);
      float p3 = exp2f((sacc[j][3] - bqv) * m3);
      float psum = (p0 + p1) + (p2 + p3);
      if (j == 0) lp0 += psum; else lp1 += psum;
      f16x4 ph;
      ph[0]=(_Float16)p0; ph[1]=(_Float16)p1; ph[2]=(_Float16)p2; ph[3]=(_Float16)p3;
      int nb = nbase >> 3;
      int off4 = nbase & 7;                       // 0 or 4
      int slot = nb ^ ((q_loc >> 1) & 3);
      *((f16x4*)(&Ps[pb][q_loc * NC + slot * 8 + off4])) = ph;
    }
  };

  // readout: 256v x 128q, K=32 (one MFMA per acc per chunk)
  auto do_RO = [&](int mb, int pb) {
    const _Float16* MVc = MVs[mb];
    const _Float16* Pc = Ps[pb];
    f16x8 av[4], bp[4];
    #pragma unroll
    for (int i = 0; i < 4; ++i) {
      int v_loc = wv * 64 + i * 16 + l15;
      av[i] = *((const f16x8*)(&MVc[v_loc * NC + ((g ^ ((v_loc >> 1) & 3)) * 8)]));
    }
    #pragma unroll
    for (int j = 0; j < 4; ++j) {
      int q_loc = wq * 64 + j * 16 + l15;
      bp[j] = *((const f16x8*)(&Pc[q_loc * NC + ((g ^ ((q_loc >> 1) & 3)) * 8)]));
    }
    __builtin_amdgcn_s_setprio(1);
    #pragma unroll
    for (int i = 0; i < 4; ++i)
      #pragma unroll
      for (int j = 0; j < 4; ++j)
        acc[i][j] = __builtin_amdgcn_mfma_f32_16x16x32_f16(av[i], bp[j], acc[i][j], 0, 0, 0);
    __builtin_amdgcn_s_setprio(0);
  };

  // ---- prologue: stage MV+MK(cBeg), MK(cBeg+1); S(cBeg) -> Ps[0]
  stage_mv(cBeg, 0);
  stage_mk(cBeg, 0);
  if (cBeg + 1 < cEnd) stage_mk(cBeg + 1, 1);
  float4 mA0 = *(const float4*)(msb + (size_t)cBeg * NC);
  asm volatile("s_waitcnt vmcnt(0)" ::: "memory");
  __builtin_amdgcn_s_barrier();
  __builtin_amdgcn_sched_barrier(0);
  do_S(0, 0, mA0);
  asm volatile("s_waitcnt lgkmcnt(0)" ::: "memory");
  __builtin_amdgcn_s_barrier();
  __builtin_amdgcn_sched_barrier(0);

  // ---- main loop: one barrier per chunk
  const int numCh = cEnd - cBeg;
  for (int i = 0; i < numCh; ++i) {
    const int ch = cBeg + i;
    const int cur = i & 1, nxt = cur ^ 1;
    const bool hv = (ch + 1 < cEnd);
    float4 mA;
    if (hv) mA = *(const float4*)(msb + (size_t)(ch + 1) * NC);
    __builtin_amdgcn_sched_barrier(0);
    if (hv) stage_mv(ch + 1, nxt);
    if (ch + 2 < cEnd) stage_mk(ch + 2, cur);
    if (hv) do_S(nxt, nxt, mA);
    do_RO(cur, cur);
    asm volatile("s_waitcnt vmcnt(0) lgkmcnt(0)" ::: "memory");
    __builtin_amdgcn_s_barrier();
    __builtin_amdgcn_sched_barrier(0);
  }

  // ---- epilogue: reduce l partials (8 contributors per q: nh x g)
  {
    int q0a = qw * 32 + l15;
    lred[q0a * 8 + nh * 4 + g] = lp0;
    lred[(q0a + 16) * 8 + nh * 4 + g] = lp1;
  }
  __syncthreads();
  if (tid < QT) {
    float s = 0.f;
    #pragma unroll
    for (int j = 0; j < 8; ++j) s += lred[tid * 8 + j];
    lpart[((size_t)(b * NS + nsp)) * HWP + qt * QT + tid] = s;
  }
  #pragma unroll
  for (int i = 0; i < 4; ++i) {
    #pragma unroll
    for (int j = 0; j < 4; ++j) {
      #pragma unroll
      for (int r = 0; r < 4; ++r) {
        int v_glob = vt * VT + wv * 64 + i * 16 + g * 4 + r;
        int q_l = qt * QT + wq * 64 + j * 16 + l15;
        pO[(((size_t)(b * NS + nsp)) * OCV + v_glob) * HWP + q_l] = acc[i][j][r];
      }
    }
  }
}

// ---- final: out = sum_s O'_s / sum_s l_s
__global__ void k_reduce(const float* __restrict__ pO, const float* __restrict__ lpart,
                         float* __restrict__ out) {
  int i = blockIdx.x * 256 + threadIdx.x;
  int q4 = i % 405;
  int rest = i / 405;
  int v = rest & (OCV - 1);
  int b = rest >> 10;
  int q = q4 * 4;
  float apx = 0.f, apy = 0.f, apz = 0.f, apw = 0.f;
  float alx = 0.f, aly = 0.f, alz = 0.f, alw = 0.f;
  #pragma unroll
  for (int s = 0; s < NS; ++s) {
    const float4 p = *((const float4*)(pO + (((size_t)(b * NS + s)) * OCV + v) * HWP + q));
    const float4 lv = *((const float4*)(lpart + ((size_t)(b * NS + s)) * HWP + q));
    apx += p.x; apy += p.y; apz += p.z; apw += p.w;
    alx += lv.x; aly += lv.y; alz += lv.z; alw += lv.w;
  }
  float4 o;
  o.x = apx / alx; o.y = apy / aly; o.z = apz / alz; o.w = apw / alw;
  *((float4*)(out + ((size_t)b * OCV + v) * HW + q)) = o;
}

extern "C" void kernel_launch(void* const* d_in, const int* in_sizes, int n_in,
                              void* d_out, int out_size, void* d_ws, size_t ws_size,
                              hipStream_t stream) {
  const float* qk = (const float*)d_in[0];
  const float* qe = (const float*)d_in[1];
  const float* mk = (const float*)d_in[2];
  const float* ms = (const float*)d_in[3];
  const float* mv = (const float*)d_in[4];
  float* out = (float*)d_out;

  const size_t sz_mvh = (size_t)2 * OCV * NTOT * 2;
  const size_t sz_mkp = (size_t)2 * NTOT * CKP * 2;
  const size_t sz_qp  = (size_t)2 * HWP * CKP * 2;
  const size_t sz_bsq = (size_t)2 * HWP * 4;
  const size_t need = sz_mvh + sz_mkp + sz_qp + sz_bsq
                    + (size_t)2 * NS * HWP * 4 + (size_t)2 * NS * OCV * HWP * 4;
  if (ws_size < need) return;

  char* p = (char*)d_ws;
  _Float16* mvh = (_Float16*)p; p += sz_mvh;
  _Float16* mkp = (_Float16*)p; p += sz_mkp;
  _Float16* qp  = (_Float16*)p; p += sz_qp;
  float* bsqw   = (float*)p;    p += sz_bsq;
  float* lpart  = (float*)p;    p += (size_t)2 * NS * HWP * 4;
  float* pO     = (float*)p;

  k_prep_mv<<<25920, 256, 0, stream>>>(mv, mvh);
  k_prep_mk<<<dim3(405, 2), 256, 0, stream>>>(mk, mkp);
  k_prep_q<<<dim3(NQT, 2), QT, 0, stream>>>(qk, qe, qp, bsqw);
  k_main<<<8 * 52, 512, 0, stream>>>(mvh, mkp, qp, bsqw, ms, pO, lpart);
  k_reduce<<<3240, 256, 0, stream>>>(pO, lpart, out);
}

// Round 6
// 546.493 us; speedup vs baseline: 1.8799x; 1.8799x over previous
//
#include <hip/hip_runtime.h>
#include <stdint.h>

// Problem constants
#define CKP 128          // packed K (mk ; mk^2)
#define OCV 1024         // O*CV
#define NTOT 25920       // T*H*W
#define HW 1620
#define HWP 1664         // padded to 13*128
#define QT 128           // q tile
#define VT 256           // v tile
#define NC 64            // n chunk
#define NQT 13
#define NS 2
#define CHUNKS_TOTAL 405
#define CHUNK_SPLIT 203

typedef _Float16 f16x8 __attribute__((ext_vector_type(8)));
typedef _Float16 f16x4 __attribute__((ext_vector_type(4)));
typedef float f32x4 __attribute__((ext_vector_type(4)));

__device__ __forceinline__ void gload_lds16(const void* g, void* l) {
  __builtin_amdgcn_global_load_lds(
      (const __attribute__((address_space(1))) uint32_t*)g,
      (__attribute__((address_space(3))) uint32_t*)l, 16, 0, 0);
}

// ---- prep: memory_value fp32 -> fp16
__global__ void k_prep_mv(const float* __restrict__ mv, _Float16* __restrict__ mvh) {
  int i = blockIdx.x * 256 + threadIdx.x;
  const float4* s = (const float4*)mv + (size_t)i * 2;
  float4 a = s[0], b = s[1];
  f16x8 o;
  o[0]=(_Float16)a.x; o[1]=(_Float16)a.y; o[2]=(_Float16)a.z; o[3]=(_Float16)a.w;
  o[4]=(_Float16)b.x; o[5]=(_Float16)b.y; o[6]=(_Float16)b.z; o[7]=(_Float16)b.w;
  *((f16x8*)mvh + i) = o;
}

// ---- prep: memory_key -> MKpack[b][n][k] fp16 (rows mk ; mk^2)
__global__ void k_prep_mk(const float* __restrict__ mk, _Float16* __restrict__ mkp) {
  __shared__ _Float16 LT[64 * CKP];
  int b = blockIdx.y, n0 = blockIdx.x * 64;
  int c4 = threadIdx.x >> 6, nl = threadIdx.x & 63;
  for (int c = c4; c < 64; c += 4) {
    float v = mk[((size_t)(b * 64 + c)) * NTOT + n0 + nl];
    LT[nl * CKP + c]      = (_Float16)v;
    LT[nl * CKP + 64 + c] = (_Float16)(v * v);
  }
  __syncthreads();
  #pragma unroll
  for (int k = 0; k < 4; ++k) {
    int idx = threadIdx.x + 256 * k;
    int n = idx >> 4, c16 = idx & 15;
    *((uint4*)(mkp + ((size_t)b * NTOT + n0 + n) * CKP + c16 * 8)) =
        *((const uint4*)(&LT[n * CKP + c16 * 8]));
  }
}

// ---- prep: Qpack[b][q][k] fp16 (rows 2*qk*qe ; -qe), bsq fp32; pad q>=1620 with 0
__global__ void k_prep_q(const float* __restrict__ qk, const float* __restrict__ qe,
                         _Float16* __restrict__ qp, float* __restrict__ bsq) {
  __shared__ _Float16 LT[QT * CKP];
  int b = blockIdx.y, q0 = blockIdx.x * QT;
  int t = threadIdx.x;
  int q = q0 + t;
  bool valid = q < HW;
  float acc = 0.f;
  for (int c = 0; c < 64; ++c) {
    float a = valid ? qk[((size_t)(b * 64 + c)) * HW + q] : 0.f;
    float e = valid ? qe[((size_t)(b * 64 + c)) * HW + q] : 0.f;
    LT[t * CKP + c]      = (_Float16)(2.f * a * e);
    LT[t * CKP + 64 + c] = (_Float16)(-e);
    acc += e * a * a;
  }
  bsq[(size_t)b * HWP + q] = acc;
  __syncthreads();
  #pragma unroll
  for (int k = 0; k < 16; ++k) {
    int idx = t + 128 * k;
    int qq = idx >> 4, c16 = idx & 15;
    *((uint4*)(qp + ((size_t)b * HWP + q0 + qq) * CKP + c16 * 8)) =
        *((const uint4*)(&LT[qq * CKP + c16 * 8]));
  }
}

// ---- fused main. Deep pipeline, counted vmcnt (T4): MV 3-buf staged 2 ahead,
// MK 2-buf staged 2 ahead, Ps single-buf (do_RO before do_S in each iter).
// Per-wave VMEM/iter = 7 (1 ms + 2 MK + 4 MV): barrier#1 vmcnt(11) lands
// MK(i-1); barrier#2 vmcnt(7) lands MV(i-1). Never vmcnt(0) in loop.
__launch_bounds__(512, 1)
__global__ void k_main(const _Float16* __restrict__ mvh, const _Float16* __restrict__ mkp,
                       const _Float16* __restrict__ qp, const float* __restrict__ bsq,
                       const float* __restrict__ ms,
                       float* __restrict__ pO, float* __restrict__ lpart) {
  const int wgid = blockIdx.x;
  const int xcd = wgid & 7, kk = wgid >> 3;    // kk in 0..25
  const int gsel = (kk >= NQT) ? 1 : 0;
  const int qt = kk - gsel * NQT;              // 0..12
  const int vt = ((xcd & 1) << 1) | gsel;      // 0..3
  const int bn = xcd >> 1;
  const int b = bn >> 1, nsp = bn & 1;

  const int tid = threadIdx.x;
  const int w = tid >> 6, l = tid & 63;
  const int l15 = l & 15, g = l >> 4;

  __shared__ _Float16 MVs[3][VT * NC];   // 3x32KB, linear dest, source pre-swizzled
  __shared__ _Float16 MKs[2][NC * CKP];  // 2x16KB
  __shared__ _Float16 Ps[QT * NC];       // 16KB (single buffer)

  const int qw = w & 3, nh = w >> 2;     // S-phase wave roles
  const int wv = w & 3, wq = w >> 2;     // readout roles

  const int cBeg = nsp ? CHUNK_SPLIT : 0;
  const int cEnd = nsp ? CHUNKS_TOTAL : CHUNK_SPLIT;
  const int numCh = cEnd - cBeg;

  // async-staging bases (chunk 0) + linear LDS byte offsets
  const char* mvb[4]; int dmv[4];
  #pragma unroll
  for (int k = 0; k < 4; ++k) {
    int idx = k * 512 + tid;
    int v = idx >> 3, s = idx & 7, j = s ^ (v & 7);
    mvb[k] = (const char*)(mvh + ((size_t)b * OCV + vt * VT + v) * NTOT + j * 8);
    dmv[k] = idx * 16;
  }
  const char* mkb[2]; int dmk[2];
  #pragma unroll
  for (int k = 0; k < 2; ++k) {
    int idx = k * 512 + tid;
    int n = idx >> 4, s = idx & 15, j = s ^ (n & 7);
    mkb[k] = (const char*)(mkp + ((size_t)b * NTOT + n) * CKP + j * 8);
    dmk[k] = idx * 16;
  }
  const float* msb = ms + (size_t)b * NTOT + nh * 32 + g * 4;

  // Q fragments + bsq in registers (chunk-invariant)
  f16x8 qreg[2][4];
  float bq[2];
  #pragma unroll
  for (int j = 0; j < 2; ++j) {
    int q_loc = qw * 32 + j * 16 + l15;
    const _Float16* qrow = qp + ((size_t)b * HWP + qt * QT + q_loc) * CKP;
    #pragma unroll
    for (int ks = 0; ks < 4; ++ks) qreg[j][ks] = *((const f16x8*)(qrow + (ks * 4 + g) * 8));
    bq[j] = bsq[(size_t)b * HWP + qt * QT + q_loc];
  }

  f32x4 acc[4][4];
  #pragma unroll
  for (int i = 0; i < 4; ++i)
    #pragma unroll
    for (int j = 0; j < 4; ++j) acc[i][j] = (f32x4)0.f;
  float lp0 = 0.f, lp1 = 0.f;

  auto stage_mv = [&](int ch, int buf) {
    size_t o = (size_t)ch * (NC * 2);
    char* d = (char*)MVs[buf];
    #pragma unroll
    for (int k = 0; k < 4; ++k) gload_lds16(mvb[k] + o, d + dmv[k]);
  };
  auto stage_mk = [&](int ch, int buf) {
    size_t o = (size_t)ch * (NC * CKP * 2);
    char* d = (char*)MKs[buf];
    #pragma unroll
    for (int k = 0; k < 2; ++k) gload_lds16(mkb[k] + o, d + dmk[k]);
  };

  auto do_S = [&](int kb, float4 mA, float4 mB) {
    const _Float16* MKc = MKs[kb];
    f32x4 sacc[2][2];
    #pragma unroll
    for (int i2 = 0; i2 < 2; ++i2)
      #pragma unroll
      for (int j = 0; j < 2; ++j) sacc[i2][j] = (f32x4)0.f;
    #pragma unroll
    for (int ks = 0; ks < 4; ++ks) {
      f16x8 af[2];
      #pragma unroll
      for (int i2 = 0; i2 < 2; ++i2) {
        int n_loc = nh * 32 + i2 * 16 + l15;
        af[i2] = *((const f16x8*)(&MKc[n_loc * CKP + (((ks * 4 + g) ^ (n_loc & 7)) * 8)]));
      }
      #pragma unroll
      for (int i2 = 0; i2 < 2; ++i2)
        #pragma unroll
        for (int j = 0; j < 2; ++j)
          sacc[i2][j] = __builtin_amdgcn_mfma_f32_16x16x32_f16(af[i2], qreg[j][ks], sacc[i2][j], 0, 0, 0);
    }
    const float K = 0.125f * 1.44269504f;
    #pragma unroll
    for (int i2 = 0; i2 < 2; ++i2) {
      int nbase = nh * 32 + i2 * 16 + g * 4;
      float m0 = (i2 ? mB.x : mA.x) * K;
      float m1 = (i2 ? mB.y : mA.y) * K;
      float m2 = (i2 ? mB.z : mA.z) * K;
      float m3 = (i2 ? mB.w : mA.w) * K;
      #pragma unroll
      for (int j = 0; j < 2; ++j) {
        int q_loc = qw * 32 + j * 16 + l15;
        float bqv = bq[j];
        float p0 = exp2f((sacc[i2][j][0] - bqv) * m0);
        float p1 = exp2f((sacc[i2][j][1] - bqv) * m1);
        float p2 = exp2f((sacc[i2][j][2] - bqv) * m2);
        float p3 = exp2f((sacc[i2][j][3] - bqv) * m3);
        float psum = (p0 + p1) + (p2 + p3);
        if (j == 0) lp0 += psum; else lp1 += psum;
        f16x4 ph;
        ph[0]=(_Float16)p0; ph[1]=(_Float16)p1; ph[2]=(_Float16)p2; ph[3]=(_Float16)p3;
        int nb = nbase >> 3;
        int off4 = nbase & 7;
        *((f16x4*)(&Ps[q_loc * NC + ((nb ^ (q_loc & 7)) * 8) + off4])) = ph;
      }
    }
  };

  auto do_RO = [&](int mb) {
    const _Float16* MVc = MVs[mb];
    #pragma unroll
    for (int ks = 0; ks < 2; ++ks) {
      f16x8 av[4], bp[4];
      #pragma unroll
      for (int i = 0; i < 4; ++i) {
        int v_loc = wv * 64 + i * 16 + l15;
        av[i] = *((const f16x8*)(&MVc[v_loc * NC + (((ks * 4 + g) ^ (v_loc & 7)) * 8)]));
      }
      #pragma unroll
      for (int j = 0; j < 4; ++j) {
        int q_loc = wq * 64 + j * 16 + l15;
        bp[j] = *((const f16x8*)(&Ps[q_loc * NC + (((ks * 4 + g) ^ (q_loc & 7)) * 8)]));
      }
      #pragma unroll
      for (int i = 0; i < 4; ++i)
        #pragma unroll
        for (int j = 0; j < 4; ++j)
          acc[i][j] = __builtin_amdgcn_mfma_f32_16x16x32_f16(av[i], bp[j], acc[i][j], 0, 0, 0);
    }
  };

  // ---- prologue: stage chunks cBeg->{0}, cBeg+1->{1}; S(cBeg) -> Ps
  stage_mk(cBeg, 0);
  stage_mv(cBeg, 0);
  stage_mk(cBeg + 1, 1);
  stage_mv(cBeg + 1, 1);
  float4 msP0 = *(const float4*)(msb + (size_t)cBeg * NC);
  float4 msP1 = *(const float4*)(msb + (size_t)cBeg * NC + 16);
  // ms pipeline regs: msA/msAh used by do_S(cBeg+1) at iter0; msB/msBh at iter1
  float4 msA  = *(const float4*)(msb + (size_t)(cBeg + 1) * NC);
  float4 msAh = *(const float4*)(msb + (size_t)(cBeg + 1) * NC + 16);
  float4 msB  = *(const float4*)(msb + (size_t)(cBeg + 2) * NC);
  float4 msBh = *(const float4*)(msb + (size_t)(cBeg + 2) * NC + 16);
  asm volatile("s_waitcnt vmcnt(0) lgkmcnt(0)" ::: "memory");
  __builtin_amdgcn_s_barrier();
  __builtin_amdgcn_sched_barrier(0);
  do_S(0, msP0, msP1);
  asm volatile("s_waitcnt lgkmcnt(0)" ::: "memory");
  __builtin_amdgcn_s_barrier();
  __builtin_amdgcn_sched_barrier(0);

  // ---- main loop
  int r0 = 0;
  for (int i = 0; i < numCh; ++i) {
    const int ch = cBeg + i;
    int r2 = r0 + 2; if (r2 >= 3) r2 -= 3;
    float4 msN = msB, msNh = msBh;
    if (i + 4 <= numCh) {               // ms for chunk ch+3, used at iter i+2
      msN  = *(const float4*)(msb + (size_t)(ch + 3) * NC);
      msNh = *(const float4*)(msb + (size_t)(ch + 3) * NC + 16);
    }
    if (i + 2 < numCh) {                // stage chunk ch+2 (2-deep prefetch)
      stage_mk(ch + 2, i & 1);
      stage_mv(ch + 2, r2);
    }
    do_RO(r0);                          // readout chunk ch (MVs[r0], Ps)
    asm volatile("s_waitcnt vmcnt(11) lgkmcnt(0)" ::: "memory");
    __builtin_amdgcn_s_barrier();
    __builtin_amdgcn_sched_barrier(0);
    if (i + 1 < numCh) do_S((i + 1) & 1, msA, msAh);  // S chunk ch+1 -> Ps
    msA = msB; msAh = msBh; msB = msN; msBh = msNh;
    asm volatile("s_waitcnt vmcnt(7) lgkmcnt(0)" ::: "memory");
    __builtin_amdgcn_s_barrier();
    __builtin_amdgcn_sched_barrier(0);
    r0 = (r0 + 1 == 3) ? 0 : r0 + 1;
  }

  // ---- epilogue: reduce l partials (lred overlays MKs; loop is done with it)
  float* lred = (float*)(&MKs[0][0]);
  {
    int q0a = qw * 32 + l15;
    lred[q0a * 8 + nh * 4 + g] = lp0;
    lred[(q0a + 16) * 8 + nh * 4 + g] = lp1;
  }
  __syncthreads();
  if (tid < QT) {
    float s = 0.f;
    #pragma unroll
    for (int j = 0; j < 8; ++j) s += lred[tid * 8 + j];
    lpart[((size_t)(b * NS + nsp)) * HWP + qt * QT + tid] = s;
  }
  #pragma unroll
  for (int i = 0; i < 4; ++i) {
    #pragma unroll
    for (int j = 0; j < 4; ++j) {
      #pragma unroll
      for (int r = 0; r < 4; ++r) {
        int v_glob = vt * VT + wv * 64 + i * 16 + g * 4 + r;
        int q_l = qt * QT + wq * 64 + j * 16 + l15;
        pO[(((size_t)(b * NS + nsp)) * OCV + v_glob) * HWP + q_l] = acc[i][j][r];
      }
    }
  }
}

// ---- final: out = sum_s O'_s / sum_s l_s
__global__ void k_reduce(const float* __restrict__ pO, const float* __restrict__ lpart,
                         float* __restrict__ out) {
  int i = blockIdx.x * 256 + threadIdx.x;
  int q4 = i % 405;
  int rest = i / 405;
  int v = rest & (OCV - 1);
  int b = rest >> 10;
  int q = q4 * 4;
  float apx = 0.f, apy = 0.f, apz = 0.f, apw = 0.f;
  float alx = 0.f, aly = 0.f, alz = 0.f, alw = 0.f;
  #pragma unroll
  for (int s = 0; s < NS; ++s) {
    const float4 p = *((const float4*)(pO + (((size_t)(b * NS + s)) * OCV + v) * HWP + q));
    const float4 lv = *((const float4*)(lpart + ((size_t)(b * NS + s)) * HWP + q));
    apx += p.x; apy += p.y; apz += p.z; apw += p.w;
    alx += lv.x; aly += lv.y; alz += lv.z; alw += lv.w;
  }
  float4 o;
  o.x = apx / alx; o.y = apy / aly; o.z = apz / alz; o.w = apw / alw;
  *((float4*)(out + ((size_t)b * OCV + v) * HW + q)) = o;
}

extern "C" void kernel_launch(void* const* d_in, const int* in_sizes, int n_in,
                              void* d_out, int out_size, void* d_ws, size_t ws_size,
                              hipStream_t stream) {
  const float* qk = (const float*)d_in[0];
  const float* qe = (const float*)d_in[1];
  const float* mk = (const float*)d_in[2];
  const float* ms = (const float*)d_in[3];
  const float* mv = (const float*)d_in[4];
  float* out = (float*)d_out;

  const size_t sz_mvh = (size_t)2 * OCV * NTOT * 2;
  const size_t sz_mkp = (size_t)2 * NTOT * CKP * 2;
  const size_t sz_qp  = (size_t)2 * HWP * CKP * 2;
  const size_t sz_bsq = (size_t)2 * HWP * 4;
  const size_t need = sz_mvh + sz_mkp + sz_qp + sz_bsq
                    + (size_t)2 * NS * HWP * 4 + (size_t)2 * NS * OCV * HWP * 4;
  if (ws_size < need) return;

  char* p = (char*)d_ws;
  _Float16* mvh = (_Float16*)p; p += sz_mvh;
  _Float16* mkp = (_Float16*)p; p += sz_mkp;
  _Float16* qp  = (_Float16*)p; p += sz_qp;
  float* bsqw   = (float*)p;    p += sz_bsq;
  float* lpart  = (float*)p;    p += (size_t)2 * NS * HWP * 4;
  float* pO     = (float*)p;

  k_prep_mv<<<25920, 256, 0, stream>>>(mv, mvh);
  k_prep_mk<<<dim3(405, 2), 256, 0, stream>>>(mk, mkp);
  k_prep_q<<<dim3(NQT, 2), QT, 0, stream>>>(qk, qe, qp, bsqw);
  k_main<<<8 * 26, 512, 0, stream>>>(mvh, mkp, qp, bsqw, ms, pO, lpart);
  k_reduce<<<3240, 256, 0, stream>>>(pO, lpart, out);
}